// Round 4
// baseline (326.499 us; speedup 1.0000x reference)
//
#include <hip/hip_runtime.h>

// Beamform: 4 channels of interleaved complex f32; per 20-complex-sample unit
// a (1x4)@(4x5) complex combine with weight vector bf (8 floats, re/im
// interleaved). Output per unit: 10 floats [re0..re4, im0..im4].
//
// Round 5b: same experiment as round 5 (NON-TEMPORAL LOADS, plain stores) —
// fixed compile error: __builtin_nontemporal_load needs a native clang
// vector type, not HIP_vector_type<float,2>. Use ext_vector_type(2).
//
// Evidence: three structurally different kernels (scalar, float4+LDS, nt-store)
// all tie at ~113-125 us. FETCH pinned at 160 MB = exactly half the 320 MB
// input: half the reads are served by Infinity Cache, half by HBM. Delivery:
// HBM 2.1 TB/s (26% of m13's proven 6.3), IF$ ~1.4 TB/s. Little's law rules
// out latency/MLP. Theory: the IF$-hit service path saturates ~1.4-1.5 TB/s;
// max(160/6.3, 160/1.4) ~ 107 us matches measured 113. m13's copy streams
// past L3 (0% hits) so it sees pure-HBM 6.3. Fix: nt loads -> no-allocate in
// L2/IF$, next dispatch reads come from HBM instead of the slow hit path.
// Prediction: FETCH 160 -> ~320 MB; dur 113 -> 70-90 us if theory right.
// Round-2's nt STORES regressed (113->123) and stay reverted.
//
// Work mapping (round-0): 5 threads per unit, thread=(bl,c). Thread reads 4
// float2 pairs x[10r+2c..+1] (r=0..3); wave's lanes cover a contiguous 2048-B
// window per load inst, L1 absorbs the 4x line re-touch.
// Output unit b = ch*bpc + bl: out[b*10 + c] = re, out[b*10 + 5 + c] = im.

typedef float v2f __attribute__((ext_vector_type(2)));

__global__ __launch_bounds__(256) void beamform_kernel(
    const float* __restrict__ in0, const float* __restrict__ in1,
    const float* __restrict__ in2, const float* __restrict__ in3,
    const float* __restrict__ bf, float* __restrict__ out,
    int blocksPerChannel, int threadsPerChannel)
{
    const int tid = blockIdx.x * blockDim.x + threadIdx.x;  // 0 .. 5*bpc-1
    if (tid >= threadsPerChannel) return;
    const int ch = blockIdx.y;  // channel 0..3

    const float* __restrict__ in =
        (ch == 0) ? in0 : (ch == 1) ? in1 : (ch == 2) ? in2 : in3;

    const int bl = tid / 5;         // unit within channel (magic-mul div)
    const int c  = tid - bl * 5;    // column 0..4

    // 4 aligned 8-B loads: x[10r+2c], x[10r+2c+1] — NON-TEMPORAL: do not
    // retain input lines in L2/IF$; they are single-touch within a dispatch,
    // and retaining them routes next-dispatch reads through the slower
    // IF$-hit path instead of HBM.
    const v2f* __restrict__ p =
        reinterpret_cast<const v2f*>(in + (size_t)bl * 40 + 2 * c);
    const v2f x0 = __builtin_nontemporal_load(p + 0);
    const v2f x1 = __builtin_nontemporal_load(p + 5);
    const v2f x2 = __builtin_nontemporal_load(p + 10);
    const v2f x3 = __builtin_nontemporal_load(p + 15);

    // Uniform beamforming weights (scalar-cached, keep temporal).
    const float br0 = bf[0], bi0 = bf[1];
    const float br1 = bf[2], bi1 = bf[3];
    const float br2 = bf[4], bi2 = bf[5];
    const float br3 = bf[6], bi3 = bf[7];

    float re = br0 * x0.x - bi0 * x0.y;
    float im = bi0 * x0.x + br0 * x0.y;
    re += br1 * x1.x - bi1 * x1.y;
    im += bi1 * x1.x + br1 * x1.y;
    re += br2 * x2.x - bi2 * x2.y;
    im += bi2 * x2.x + br2 * x2.y;
    re += br3 * x3.x - bi3 * x3.y;
    im += bi3 * x3.x + br3 * x3.y;

    const size_t b = (size_t)ch * blocksPerChannel + bl;
    float* __restrict__ o = out + b * 10;
    o[c] = re;          // plain stores (round-2 nt stores were -8%)
    o[5 + c] = im;
}

extern "C" void kernel_launch(void* const* d_in, const int* in_sizes, int n_in,
                              void* d_out, int out_size, void* d_ws, size_t ws_size,
                              hipStream_t stream)
{
    const float* in0 = (const float*)d_in[0];
    const float* in1 = (const float*)d_in[1];
    const float* in2 = (const float*)d_in[2];
    const float* in3 = (const float*)d_in[3];
    const float* bf  = (const float*)d_in[4];
    float* out = (float*)d_out;

    const int len = in_sizes[0];               // 20,000,000 interleaved floats
    const int blocksPerChannel = len / 40;     // 500,000 units / channel
    const int threadsPerChannel = blocksPerChannel * 5;

    const int block = 256;
    dim3 grid((threadsPerChannel + block - 1) / block, 4, 1);
    beamform_kernel<<<grid, dim3(block, 1, 1), 0, stream>>>(
        in0, in1, in2, in3, bf, out, blocksPerChannel, threadsPerChannel);
}

// Round 5
// 292.400 us; speedup vs baseline: 1.1166x; 1.1166x over previous
//
#include <hip/hip_runtime.h>

// Beamform: 4 channels of interleaved complex f32; per 20-complex-sample unit
// a (1x4)@(4x5) complex combine with weight vector bf (8 floats, re/im
// interleaved). Output per unit: 10 floats [re0..re4, im0..im4].
//
// FINAL (round 5): revert to the best-verified variant (round-0 body).
// Session evidence — five structurally independent experiments:
//   R0 scalar/no-LDS (this kernel)        : 113.7 us/dispatch  <- best
//   R1 float4 + LDS transpose, coalesced  : 115.1 us (shape exonerated)
//   R2 non-temporal stores                : 123.0 us (regression)
//   R4 non-temporal loads                 : 118.6 us (FETCH unchanged; hint
//                                           inert at L2/IF$ on reads)
// Counters pinned across all variants: FETCH ~160 MB (= half of the 320 MB
// input; other half served by the 256 MB Infinity Cache), WRITE ~80 MB,
// VALUBusy ~9%, zero LDS conflicts, occupancy 36-76% irrelevant, in-flight
// bytes up to 7x BDP (rules out latency/MLP). Logical delivery is pinned at
// ~3.5 TB/s for this 4-read-stream + 1-write-stream, 50%-L3-resident mix.
// Structural floor: 400 MB/dispatch minimum traffic -> ~113 us at that
// delivery rate, which is precisely where this kernel sits. No kernel-side
// lever (shape, occupancy, MLP, store policy, load policy) moves it.
//
// Work mapping: 5 threads per unit, thread=(bl,c). Thread reads 4 float2
// pairs x[10r+2c..+1] (r=0..3); a wave's 64 lanes cover a contiguous 2048-B
// window per load instruction, L1 absorbs the 4x line re-touch.
// Output unit b = ch*bpc + bl: out[b*10 + c] = re, out[b*10 + 5 + c] = im.

__global__ __launch_bounds__(256) void beamform_kernel(
    const float* __restrict__ in0, const float* __restrict__ in1,
    const float* __restrict__ in2, const float* __restrict__ in3,
    const float* __restrict__ bf, float* __restrict__ out,
    int blocksPerChannel, int threadsPerChannel)
{
    const int tid = blockIdx.x * blockDim.x + threadIdx.x;  // 0 .. 5*bpc-1
    if (tid >= threadsPerChannel) return;
    const int ch = blockIdx.y;  // channel 0..3

    const float* __restrict__ in =
        (ch == 0) ? in0 : (ch == 1) ? in1 : (ch == 2) ? in2 : in3;

    const int bl = tid / 5;         // unit within channel (magic-mul div)
    const int c  = tid - bl * 5;    // column 0..4

    // 4 aligned float2 loads: x[10r+2c], x[10r+2c+1]
    const float2* __restrict__ p =
        reinterpret_cast<const float2*>(in + (size_t)bl * 40 + 2 * c);
    // p is float2-indexed: element (10r+2c)/2 = 5r + c relative to bl*20
    const float2 x0 = p[0];
    const float2 x1 = p[5];
    const float2 x2 = p[10];
    const float2 x3 = p[15];

    // Uniform beamforming weights (scalar-cached).
    const float br0 = bf[0], bi0 = bf[1];
    const float br1 = bf[2], bi1 = bf[3];
    const float br2 = bf[4], bi2 = bf[5];
    const float br3 = bf[6], bi3 = bf[7];

    float re = br0 * x0.x - bi0 * x0.y;
    float im = bi0 * x0.x + br0 * x0.y;
    re += br1 * x1.x - bi1 * x1.y;
    im += bi1 * x1.x + br1 * x1.y;
    re += br2 * x2.x - bi2 * x2.y;
    im += bi2 * x2.x + br2 * x2.y;
    re += br3 * x3.x - bi3 * x3.y;
    im += bi3 * x3.x + br3 * x3.y;

    const size_t b = (size_t)ch * blocksPerChannel + bl;
    float* __restrict__ o = out + b * 10;
    o[c] = re;
    o[5 + c] = im;
}

extern "C" void kernel_launch(void* const* d_in, const int* in_sizes, int n_in,
                              void* d_out, int out_size, void* d_ws, size_t ws_size,
                              hipStream_t stream)
{
    const float* in0 = (const float*)d_in[0];
    const float* in1 = (const float*)d_in[1];
    const float* in2 = (const float*)d_in[2];
    const float* in3 = (const float*)d_in[3];
    const float* bf  = (const float*)d_in[4];
    float* out = (float*)d_out;

    const int len = in_sizes[0];               // 20,000,000 interleaved floats
    const int blocksPerChannel = len / 40;     // 500,000 units / channel
    const int threadsPerChannel = blocksPerChannel * 5;

    const int block = 256;
    dim3 grid((threadsPerChannel + block - 1) / block, 4, 1);
    beamform_kernel<<<grid, dim3(block, 1, 1), 0, stream>>>(
        in0, in1, in2, in3, bf, out, blocksPerChannel, threadsPerChannel);
}